// Round 10
// baseline (457.952 us; speedup 1.0000x reference)
//
#include <hip/hip_runtime.h>
#include <cstdint>
#include <cstddef>

#define N_ANCH   120000
#define K_PRE    2000
#define K_POST   512
#define CAP      4096
#define NWORD    32          // ceil(K_PRE/64)
#define HBINS    4096        // top-12-bit histogram
#define IOU_THR  0.7f
#define IMGF     800.0f
#define CLIPV    4.135166556742356f
#define FH       200
#define FW       200
#define FC       256
#define SCALE    0.25f

#define TROWS    96          // scan tile rows (96*256B = 24KB; x2 buffers = 48KB LDS)
#define NTILE    21          // ceil(2000/96); last tile = 80 rows
#define CH       8           // scan chunk rows (register prefetch depth)

#define TPE      4           // rank: threads per element
#define SPAN     201         // roi: max x-span (<=200) + 1 pad

typedef unsigned long long u64;

struct Ws {
    uint32_t T;          // threshold key (bucket lower edge)
    uint32_t cnt;        // gather counter
    int32_t  nk;         // number kept after NMS
    uint32_t pad;
    u64      combo[CAP];             // (~key)<<32 | index (unsorted)
    float4   cand[K_PRE];            // decoded candidate boxes, score-desc order
    int      rows[K_POST];           // candidate rank per output row, -1 = invalid
    u64      mask[(size_t)K_PRE * NWORD];  // IoU bitmask, ALL 32 words written
    // NOTE: first 16KB of mask doubles as the uint32 hist[4096] (used before mask)
};

// Monotonic float -> uint key (larger float => larger uint). No NaNs expected.
__device__ inline uint32_t fkey(float f) {
    uint32_t u = __float_as_uint(f);
    return (u & 0x80000000u) ? ~u : (u | 0x80000000u);
}

// ---------------------------------------------------------------------------
// Kernel 0: zero the histogram (aliased onto mask region) + counters.
// ---------------------------------------------------------------------------
__global__ __launch_bounds__(1024) void zero_k(Ws* __restrict__ ws) {
    uint32_t* h = (uint32_t*)ws->mask;
    for (int i = threadIdx.x; i < HBINS; i += 1024) h[i] = 0u;
    if (threadIdx.x == 0) { ws->cnt = 0u; ws->nk = 0; ws->T = 0u; }
}

// ---------------------------------------------------------------------------
// Kernel 1: grid-wide 4096-bin histogram of top-12 key bits (LDS-privatized).
// ---------------------------------------------------------------------------
__global__ __launch_bounds__(256) void hist_k(const float* __restrict__ obj,
                                              uint32_t* __restrict__ hist) {
    __shared__ uint32_t h[HBINS];
    for (int i = threadIdx.x; i < HBINS; i += 256) h[i] = 0u;
    __syncthreads();
    const float4* o4 = (const float4*)obj;
    for (int i = blockIdx.x * 256 + threadIdx.x; i < N_ANCH / 4; i += gridDim.x * 256) {
        float4 v = o4[i];
        atomicAdd(&h[fkey(v.x) >> 20], 1u);
        atomicAdd(&h[fkey(v.y) >> 20], 1u);
        atomicAdd(&h[fkey(v.z) >> 20], 1u);
        atomicAdd(&h[fkey(v.w) >> 20], 1u);
    }
    __syncthreads();
    for (int i = threadIdx.x; i < HBINS; i += 256)
        if (h[i]) atomicAdd(&hist[i], h[i]);
}

// ---------------------------------------------------------------------------
// Kernel 2: find threshold bucket: largest bin B with suffix-count >= K_PRE.
// ---------------------------------------------------------------------------
__global__ __launch_bounds__(1024) void resolve_k(const uint32_t* __restrict__ hist,
                                                  Ws* __restrict__ ws) {
    __shared__ uint32_t wsum[16];
    const int tid = threadIdx.x;
    const int lane = tid & 63, wave = tid >> 6;
    uint32_t c[4]; uint32_t s = 0;
#pragma unroll
    for (int k = 0; k < 4; ++k) { c[k] = hist[HBINS - 1 - (4 * tid + k)]; s += c[k]; }
    uint32_t incl = s;
    for (int off = 1; off < 64; off <<= 1) {
        uint32_t t = __shfl_up(incl, off);
        if (lane >= off) incl += t;
    }
    if (lane == 63) wsum[wave] = incl;
    __syncthreads();
    uint32_t wpre = 0;
    for (int w2 = 0; w2 < wave; ++w2) wpre += wsum[w2];
    uint32_t before = wpre + incl - s;
#pragma unroll
    for (int k = 0; k < 4; ++k) {
        uint32_t after = before + c[k];
        if (before < K_PRE && after >= K_PRE)
            ws->T = (uint32_t)(HBINS - 1 - (4 * tid + k)) << 20;
        before = after;
    }
}

// ---------------------------------------------------------------------------
// Kernel 3: grid-wide gather of all elements with key >= T (float4 loads).
// ---------------------------------------------------------------------------
__global__ void gather_k(const float* __restrict__ obj, Ws* __restrict__ ws) {
    int i = blockIdx.x * blockDim.x + threadIdx.x;
    if (i >= N_ANCH / 4) return;
    const uint32_t T = ws->T;
    float4 v = ((const float4*)obj)[i];
    float vals[4] = {v.x, v.y, v.z, v.w};
#pragma unroll
    for (int k = 0; k < 4; ++k) {
        uint32_t u = fkey(vals[k]);
        if (u >= T) {
            uint32_t pos = atomicAdd(&ws->cnt, 1u);
            if (pos < CAP)
                ws->combo[pos] = ((u64)(~u) << 32) | (uint32_t)(4 * i + k);
        }
    }
}

// ---------------------------------------------------------------------------
// Kernel 4: RANK-based ordering. Combos are distinct, so sorted position ==
// rank == #{j: combo[j] < combo[i]} (= score desc, index asc — exact
// lax.top_k order). TPE=4 threads per element count strided quarters over
// LDS-staged combos; winner decodes straight into cand[rank].
// ---------------------------------------------------------------------------
__global__ __launch_bounds__(256) void rank_decode_k(const float* __restrict__ deltas,
                                                     const float* __restrict__ anchors,
                                                     Ws* __restrict__ ws) {
    __shared__ u64 sc[CAP];
    const int tid = threadIdx.x;
    int M = (int)ws->cnt;
    if (M > CAP) M = CAP;
    const int ebase = blockIdx.x * (256 / TPE);
    if (ebase >= M) return;
    for (int e = tid; e < M; e += 256) sc[e] = ws->combo[e];
    __syncthreads();
    const int gid = ebase + tid / TPE;
    const int sub = tid & (TPE - 1);
    if (gid >= M) return;
    const u64 mine = sc[gid];
    int cnt = 0;
    int j = sub;
    for (; j + 3 * TPE < M; j += 4 * TPE) {
        u64 a = sc[j], b = sc[j + TPE], c = sc[j + 2 * TPE], d = sc[j + 3 * TPE];
        cnt += (int)(a < mine) + (int)(b < mine) + (int)(c < mine) + (int)(d < mine);
    }
    for (; j < M; j += TPE) cnt += (int)(sc[j] < mine);
    cnt += __shfl_xor(cnt, 1);
    cnt += __shfl_xor(cnt, 2);
    if (sub == 0 && cnt < K_PRE) {
        const uint32_t idx = (uint32_t)(mine & 0xFFFFFFFFull);
        float a0 = anchors[idx * 4 + 0], a1 = anchors[idx * 4 + 1];
        float a2 = anchors[idx * 4 + 2], a3 = anchors[idx * 4 + 3];
        float d0 = deltas[idx * 4 + 0],  d1 = deltas[idx * 4 + 1];
        float d2 = fminf(deltas[idx * 4 + 2], CLIPV);
        float d3 = fminf(deltas[idx * 4 + 3], CLIPV);
        float w = a2 - a0, h = a3 - a1;
        float cx = a0 + 0.5f * w, cy = a1 + 0.5f * h;
        float pcx = d0 * w + cx, pcy = d1 * h + cy;
        float pw = expf(d2) * w, ph = expf(d3) * h;
        float x1 = fminf(fmaxf(pcx - 0.5f * pw, 0.0f), IMGF);
        float y1 = fminf(fmaxf(pcy - 0.5f * ph, 0.0f), IMGF);
        float x2 = fminf(fmaxf(pcx + 0.5f * pw, 0.0f), IMGF);
        float y2 = fminf(fmaxf(pcy + 0.5f * ph, 0.0f), IMGF);
        ws->cand[cnt] = make_float4(x1, y1, x2, y2);
    }
}

// ---------------------------------------------------------------------------
// Kernel 5a: build the pairwise suppression bitmask.
// ---------------------------------------------------------------------------
__global__ __launch_bounds__(256) void nms_mask_k(Ws* __restrict__ ws) {
    const int i = blockIdx.x;
    const int lane = threadIdx.x & 63;
    const int wave = threadIdx.x >> 6;
    const float4 bi = ws->cand[i];
    const float ai = (bi.z - bi.x) * (bi.w - bi.y);
    for (int wd = wave; wd < NWORD; wd += 4) {
        int j = wd * 64 + lane;
        bool bit = false;
        if (j < K_PRE && j > i) {
            float4 bj = ws->cand[j];
            float aj = (bj.z - bj.x) * (bj.w - bj.y);
            float xx1 = fmaxf(bi.x, bj.x);
            float yy1 = fmaxf(bi.y, bj.y);
            float xx2 = fminf(bi.z, bj.z);
            float yy2 = fminf(bi.w, bj.w);
            float ww = fmaxf(xx2 - xx1, 0.0f);
            float hh = fmaxf(yy2 - yy1, 0.0f);
            float inter = ww * hh;
            float iou = inter / (ai + aj - inter + 1e-6f);
            bit = iou > IOU_THR;
        }
        u64 bal = __ballot(bit);
        if (lane == 0) ws->mask[(size_t)i * NWORD + wd] = bal;
    }
}

// ---------------------------------------------------------------------------
// Kernel 5b: greedy scan, owner-lane formulation + early exit once K_POST
// rows are kept (downstream only consumes the first K_POST kept rows).
// ---------------------------------------------------------------------------
__global__ __launch_bounds__(512) void nms_scan_k(Ws* __restrict__ ws) {
    __shared__ __align__(16) u64 sbuf[2][TROWS * NWORD];
    __shared__ int s_stop;
    const int tid = threadIdx.x;
    const int lane = tid & 63;
    const int wave = tid >> 6;
    const int lmod = lane & 31;
    const u64* __restrict__ mask = ws->mask;

    {
        const ulonglong2* src = (const ulonglong2*)mask;
        ulonglong2* dst = (ulonglong2*)sbuf[0];
        for (int e = tid; e < TROWS * NWORD / 2; e += 512) dst[e] = src[e];
    }
    if (tid == 0) s_stop = 0;
    __syncthreads();

    u64 supp = 0ull;
    int kcnt = 0;
    int decided = 0;
    for (int t = 0; t < NTILE; ++t) {
        const int base = t * TROWS;
        const int nb = min(TROWS, K_PRE - base);
        if (wave == 0) {
            const u64* sm = sbuf[t & 1];
            u64 A[CH], B[CH];
#pragma unroll
            for (int b = 0; b < CH; ++b) A[b] = sm[b * NWORD + lmod];
            for (int s = 0; s < nb; s += 2 * CH) {
                const bool hasB = (s + CH) < nb;
                if (hasB) {
#pragma unroll
                    for (int b = 0; b < CH; ++b) B[b] = sm[(s + CH + b) * NWORD + lmod];
                }
                {
                    const int w = (base + s) >> 6;
                    const int bofs = (base + s) & 63;
                    u64 keptw = 0ull;
                    if (lane == w) {
                        u64 cur = supp;
#pragma unroll
                        for (int b = 0; b < CH; ++b) {
                            u64 bit = (cur >> (bofs + b)) & 1ull;
                            u64 sel = bit - 1ull;
                            cur |= A[b] & sel;
                            keptw |= sel & (1ull << b);
                        }
                        supp = cur;
                    }
                    u64 kb = __shfl(keptw, w);
                    kcnt += __popcll(kb);
#pragma unroll
                    for (int b = 0; b < CH; ++b) {
                        u64 sel = 0ull - ((kb >> b) & 1ull);
                        supp |= A[b] & sel;
                    }
                }
                if (hasB) {
                    if (s + 2 * CH < nb) {
#pragma unroll
                        for (int b = 0; b < CH; ++b)
                            A[b] = sm[(s + 2 * CH + b) * NWORD + lmod];
                    }
                    const int w = (base + s + CH) >> 6;
                    const int bofs = (base + s + CH) & 63;
                    u64 keptw = 0ull;
                    if (lane == w) {
                        u64 cur = supp;
#pragma unroll
                        for (int b = 0; b < CH; ++b) {
                            u64 bit = (cur >> (bofs + b)) & 1ull;
                            u64 sel = bit - 1ull;
                            cur |= B[b] & sel;
                            keptw |= sel & (1ull << b);
                        }
                        supp = cur;
                    }
                    u64 kb = __shfl(keptw, w);
                    kcnt += __popcll(kb);
#pragma unroll
                    for (int b = 0; b < CH; ++b) {
                        u64 sel = 0ull - ((kb >> b) & 1ull);
                        supp |= B[b] & sel;
                    }
                }
            }
            decided = base + nb;
            if (lane == 0 && kcnt >= K_POST) s_stop = 1;
        } else if (t + 1 < NTILE) {
            const int nbase = (t + 1) * TROWS;
            const int npairs = (min(TROWS, K_PRE - nbase) * NWORD) / 2;
            const ulonglong2* src = (const ulonglong2*)(mask + (size_t)nbase * NWORD);
            ulonglong2* dst = (ulonglong2*)sbuf[(t + 1) & 1];
            for (int e = tid - 64; e < npairs; e += 448) dst[e] = src[e];
        }
        __syncthreads();
        if (s_stop) break;
    }

    if (wave == 0) {
        u64 valid;
        if (lane < NWORD - 1)       valid = ~0ull;
        else if (lane == NWORD - 1) valid = (1ull << (K_PRE - (NWORD - 1) * 64)) - 1ull;
        else                        valid = 0ull;
        const int dw = decided - lane * 64;
        const u64 dmask = (dw <= 0) ? 0ull : ((dw >= 64) ? ~0ull : ((1ull << dw) - 1ull));
        u64 keepw = (~supp) & valid & dmask;
        int cnt = __popcll(keepw);
        int incl = cnt;
        for (int off = 1; off < 64; off <<= 1) {
            int t = __shfl_up(incl, off);
            if (lane >= off) incl += t;
        }
        int pos = incl - cnt;
        u64 kw = keepw;
        while (kw) {
            int b = __ffsll((unsigned long long)kw) - 1;
            kw &= kw - 1ull;
            if (pos < K_POST) ws->rows[pos] = lane * 64 + b;
            ++pos;
        }
        int total = __shfl(incl, 63);
        if (lane == 0) ws->nk = total;
        int start = total < K_POST ? total : K_POST;
        for (int r = start + lane; r < K_POST; r += 64) ws->rows[r] = -1;
    }
}

// ---------------------------------------------------------------------------
// Kernel 6: ROIAlign via row-span LDS staging (round-9 lesson: scattered
// gathers pay the TA per distinct cache line PER INSTRUCTION — 51M lane-
// gathers ~= 57us even with data L2-resident). One block per (roi, channel):
//  1. stage the <=28 needed feature rows (14 sample-ys x 2 corners) as
//     CONTIGUOUS x-spans into LDS — consecutive lanes, consecutive floats,
//     each cache line touched once.
//  2. 196 threads compute one bilinear sample each from LDS.
//  3. 49 threads reduce 2x2 samples -> bin, coalesced 49-float store.
// Clamp edges use the verified base-shift trick: base=min(idx,FW-2) with
// weight (0,1) at the boundary — exact because clamped coords have zero frac
// there. XCD affinity: c = (blk&7)*32 + ((blk>>3)&31).
// ---------------------------------------------------------------------------
__global__ __launch_bounds__(256) void roi_k(const float* __restrict__ feat,
                                             const Ws* __restrict__ ws,
                                             float* __restrict__ out) {
    __shared__ float ltile[28 * SPAN];
    __shared__ float smpl[196];
    __shared__ int s_iyb[14];
    const int blk = blockIdx.x;
    const int r = blk >> 8;
    const int c = (blk & 7) * 32 + ((blk >> 3) & 31);
    float* orow = out + (size_t)r * (FC * 49) + (size_t)c * 49;
    const int row = ws->rows[r];
    const int tid = threadIdx.x;
    if (row < 0) {
        if (tid < 49) orow[tid] = 0.0f;
        return;
    }

    const float4 bx = ws->cand[row];
    const float x1 = bx.x * SCALE, y1 = bx.y * SCALE;
    const float x2 = bx.z * SCALE, y2 = bx.w * SCALE;
    const float rw = fmaxf(x2 - x1, 1.0f);
    const float rh = fmaxf(y2 - y1, 1.0f);
    const float stepx = rw / 14.0f;
    const float stepy = rh / 14.0f;

    // uniform x-span: base_x monotone in sx -> xlo = base(0), xhi = base(13)+1
    auto xbase = [&](int sx) {
        float xx = x1 + ((float)sx + 0.5f) * stepx;
        float x = fminf(fmaxf(xx, 0.0f), (float)(FW - 1));
        return min((int)floorf(x), FW - 2);
    };
    const int xlo = xbase(0);
    const int span = xbase(13) + 2 - xlo;          // <= 200

    if (tid < 14) {
        float yy = y1 + ((float)tid + 0.5f) * stepy;
        float y = fminf(fmaxf(yy, 0.0f), (float)(FH - 1));
        s_iyb[tid] = min((int)floorf(y), FH - 2);
    }
    __syncthreads();

    // stage 28 rows; wave w handles rows w, w+4, ... (lanes coalesced in x)
    {
        const int lane = tid & 63;
        const int wave = tid >> 6;
        const float* fc = feat + (size_t)c * (FH * FW);
        for (int rr = wave; rr < 28; rr += 4) {
            const int iy = s_iyb[rr >> 1] + (rr & 1);
            const float* src = fc + iy * FW + xlo;
            float* dst = ltile + rr * SPAN;
            for (int x = lane; x < span; x += 64) dst[x] = src[x];
        }
    }
    __syncthreads();

    if (tid < 196) {
        const int sy = tid / 14, sx = tid % 14;
        float yy = y1 + ((float)sy + 0.5f) * stepy;
        float y = fminf(fmaxf(yy, 0.0f), (float)(FH - 1));
        const int iyb = s_iyb[sy];
        const float wy1 = y - (float)iyb;           // ==ly normally; ==1 at edge
        const float wy0 = 1.0f - wy1;
        float xx = x1 + ((float)sx + 0.5f) * stepx;
        float x = fminf(fmaxf(xx, 0.0f), (float)(FW - 1));
        const int xb = min((int)floorf(x), FW - 2);
        const float wx1 = x - (float)xb;
        const float wx0 = 1.0f - wx1;
        const int xo = xb - xlo;
        const float* r0 = ltile + (2 * sy) * SPAN;
        const float* r1 = r0 + SPAN;
        smpl[tid] = wy0 * (wx0 * r0[xo] + wx1 * r0[xo + 1])
                  + wy1 * (wx0 * r1[xo] + wx1 * r1[xo + 1]);
    }
    __syncthreads();

    if (tid < 49) {
        const int by = tid / 7, bx2 = tid % 7;
        const int s0 = (2 * by) * 14 + 2 * bx2;
        float sum = smpl[s0] + smpl[s0 + 1] + smpl[s0 + 14] + smpl[s0 + 15];
        orow[tid] = sum * 0.25f;
    }
}

extern "C" void kernel_launch(void* const* d_in, const int* in_sizes, int n_in,
                              void* d_out, int out_size, void* d_ws, size_t ws_size,
                              hipStream_t stream) {
    const float* feature    = (const float*)d_in[0];
    const float* objectness = (const float*)d_in[1];
    const float* deltas     = (const float*)d_in[2];
    const float* anchors    = (const float*)d_in[3];
    Ws* ws = (Ws*)d_ws;
    uint32_t* hist = (uint32_t*)ws->mask;   // alias: hist lives in (pre-)mask space
    float* out = (float*)d_out;

    hipLaunchKernelGGL(zero_k, dim3(1), dim3(1024), 0, stream, ws);
    hipLaunchKernelGGL(hist_k, dim3(256), dim3(256), 0, stream, objectness, hist);
    hipLaunchKernelGGL(resolve_k, dim3(1), dim3(1024), 0, stream, hist, ws);
    hipLaunchKernelGGL(gather_k, dim3((N_ANCH / 4 + 255) / 256), dim3(256), 0, stream,
                       objectness, ws);
    hipLaunchKernelGGL(rank_decode_k, dim3(CAP / (256 / TPE)), dim3(256), 0, stream,
                       deltas, anchors, ws);
    hipLaunchKernelGGL(nms_mask_k, dim3(K_PRE), dim3(256), 0, stream, ws);
    hipLaunchKernelGGL(nms_scan_k, dim3(1), dim3(512), 0, stream, ws);
    hipLaunchKernelGGL(roi_k, dim3(K_POST * 256), dim3(256), 0, stream, feature, ws, out);
}

// Round 11
// 207.314 us; speedup vs baseline: 2.2090x; 2.2090x over previous
//
#include <hip/hip_runtime.h>
#include <cstdint>
#include <cstddef>

#define N_ANCH   120000
#define K_PRE    2000
#define K_POST   512
#define CAP      4096
#define NWORD    32          // ceil(K_PRE/64)
#define HBINS    4096        // top-12-bit histogram
#define IOU_THR  0.7f
#define IMGF     800.0f
#define CLIPV    4.135166556742356f
#define FH       200
#define FW       200
#define FC       256
#define SCALE    0.25f

#define TROWS    96          // scan tile rows (96*256B = 24KB; x2 buffers = 48KB LDS)
#define NTILE    21          // ceil(2000/96); last tile = 80 rows
#define CH       8           // scan chunk rows (register prefetch depth)

#define CG       32          // roi: channels per group (FC/8 -> one group per XCD)
#define TPE      4           // rank: threads per element

typedef unsigned long long u64;
// float2 with declared 4B alignment: compiler emits dwordx2; gfx9+ amdhsa
// unaligned-access-mode handles 4B-aligned 8B loads in HW.
typedef float f2u __attribute__((ext_vector_type(2), aligned(4)));

struct Ws {
    uint32_t T;          // (unused — kept for layout stability)
    uint32_t cnt;        // gather counter
    int32_t  nk;         // number kept after NMS
    uint32_t pad;
    u64      combo[CAP];             // (~key)<<32 | index (unsorted)
    float4   cand[K_PRE];            // decoded candidate boxes, score-desc order
    int      rows[K_POST];           // candidate rank per output row, -1 = invalid
    u64      mask[(size_t)K_PRE * NWORD];  // IoU bitmask, ALL 32 words written
    // NOTE: first 16KB of mask doubles as the uint32 hist[4096] (used before mask)
};

// Monotonic float -> uint key (larger float => larger uint). No NaNs expected.
__device__ inline uint32_t fkey(float f) {
    uint32_t u = __float_as_uint(f);
    return (u & 0x80000000u) ? ~u : (u | 0x80000000u);
}

// ---------------------------------------------------------------------------
// Kernel 0: zero the histogram (aliased onto mask region) + counters.
// ---------------------------------------------------------------------------
__global__ __launch_bounds__(1024) void zero_k(Ws* __restrict__ ws) {
    uint32_t* h = (uint32_t*)ws->mask;
    for (int i = threadIdx.x; i < HBINS; i += 1024) h[i] = 0u;
    if (threadIdx.x == 0) { ws->cnt = 0u; ws->nk = 0; ws->T = 0u; }
}

// ---------------------------------------------------------------------------
// Kernel 1: grid-wide 4096-bin histogram of top-12 key bits (LDS-privatized).
// ---------------------------------------------------------------------------
__global__ __launch_bounds__(256) void hist_k(const float* __restrict__ obj,
                                              uint32_t* __restrict__ hist) {
    __shared__ uint32_t h[HBINS];
    for (int i = threadIdx.x; i < HBINS; i += 256) h[i] = 0u;
    __syncthreads();
    const float4* o4 = (const float4*)obj;
    for (int i = blockIdx.x * 256 + threadIdx.x; i < N_ANCH / 4; i += gridDim.x * 256) {
        float4 v = o4[i];
        atomicAdd(&h[fkey(v.x) >> 20], 1u);
        atomicAdd(&h[fkey(v.y) >> 20], 1u);
        atomicAdd(&h[fkey(v.z) >> 20], 1u);
        atomicAdd(&h[fkey(v.w) >> 20], 1u);
    }
    __syncthreads();
    for (int i = threadIdx.x; i < HBINS; i += 256)
        if (h[i]) atomicAdd(&hist[i], h[i]);
}

// ---------------------------------------------------------------------------
// Kernel 2 (fused resolve+gather): each block redundantly computes the
// threshold bucket T from the histogram (4096 L2 reads + block scan, ~2us,
// fully parallel across blocks — round-10 change: removes the separate
// single-block resolve_k launch + its dependency gap), then gathers all
// elements with key >= T (float4 loads).
// ---------------------------------------------------------------------------
__global__ __launch_bounds__(256) void gather_k(const float* __restrict__ obj,
                                                const uint32_t* __restrict__ hist,
                                                Ws* __restrict__ ws) {
    __shared__ uint32_t wsum[4];
    __shared__ uint32_t sT;
    const int tid = threadIdx.x;
    const int lane = tid & 63, wave = tid >> 6;
    // ---- per-block threshold resolve: largest bin B with suffix >= K_PRE ----
    uint32_t c[16]; uint32_t s = 0;
#pragma unroll
    for (int k = 0; k < 16; ++k) { c[k] = hist[HBINS - 1 - (16 * tid + k)]; s += c[k]; }
    uint32_t incl = s;
    for (int off = 1; off < 64; off <<= 1) {
        uint32_t t = __shfl_up(incl, off);
        if (lane >= off) incl += t;
    }
    if (lane == 63) wsum[wave] = incl;
    __syncthreads();
    uint32_t wpre = 0;
    for (int w2 = 0; w2 < wave; ++w2) wpre += wsum[w2];
    uint32_t before = wpre + incl - s;
#pragma unroll
    for (int k = 0; k < 16; ++k) {
        uint32_t after = before + c[k];
        if (before < K_PRE && after >= K_PRE)
            sT = (uint32_t)(HBINS - 1 - (16 * tid + k)) << 20;
        before = after;
    }
    __syncthreads();
    const uint32_t T = sT;
    // ---- gather ----
    int i = blockIdx.x * 256 + tid;
    if (i >= N_ANCH / 4) return;
    float4 v = ((const float4*)obj)[i];
    float vals[4] = {v.x, v.y, v.z, v.w};
#pragma unroll
    for (int k = 0; k < 4; ++k) {
        uint32_t u = fkey(vals[k]);
        if (u >= T) {
            uint32_t pos = atomicAdd(&ws->cnt, 1u);
            if (pos < CAP)
                ws->combo[pos] = ((u64)(~u) << 32) | (uint32_t)(4 * i + k);
        }
    }
}

// ---------------------------------------------------------------------------
// Kernel 3: RANK-based ordering. Combos are distinct, so sorted position ==
// rank == #{j: combo[j] < combo[i]} (= score desc, index asc — exact
// lax.top_k order). TPE=4 threads per element count strided quarters over
// LDS-staged combos; winner decodes straight into cand[rank].
// ---------------------------------------------------------------------------
__global__ __launch_bounds__(256) void rank_decode_k(const float* __restrict__ deltas,
                                                     const float* __restrict__ anchors,
                                                     Ws* __restrict__ ws) {
    __shared__ u64 sc[CAP];
    const int tid = threadIdx.x;
    int M = (int)ws->cnt;
    if (M > CAP) M = CAP;
    const int ebase = blockIdx.x * (256 / TPE);
    if (ebase >= M) return;
    for (int e = tid; e < M; e += 256) sc[e] = ws->combo[e];
    __syncthreads();
    const int gid = ebase + tid / TPE;
    const int sub = tid & (TPE - 1);
    if (gid >= M) return;
    const u64 mine = sc[gid];
    int cnt = 0;
    int j = sub;
    for (; j + 3 * TPE < M; j += 4 * TPE) {
        u64 a = sc[j], b = sc[j + TPE], c = sc[j + 2 * TPE], d = sc[j + 3 * TPE];
        cnt += (int)(a < mine) + (int)(b < mine) + (int)(c < mine) + (int)(d < mine);
    }
    for (; j < M; j += TPE) cnt += (int)(sc[j] < mine);
    cnt += __shfl_xor(cnt, 1);
    cnt += __shfl_xor(cnt, 2);
    if (sub == 0 && cnt < K_PRE) {
        const uint32_t idx = (uint32_t)(mine & 0xFFFFFFFFull);
        float a0 = anchors[idx * 4 + 0], a1 = anchors[idx * 4 + 1];
        float a2 = anchors[idx * 4 + 2], a3 = anchors[idx * 4 + 3];
        float d0 = deltas[idx * 4 + 0],  d1 = deltas[idx * 4 + 1];
        float d2 = fminf(deltas[idx * 4 + 2], CLIPV);
        float d3 = fminf(deltas[idx * 4 + 3], CLIPV);
        float w = a2 - a0, h = a3 - a1;
        float cx = a0 + 0.5f * w, cy = a1 + 0.5f * h;
        float pcx = d0 * w + cx, pcy = d1 * h + cy;
        float pw = expf(d2) * w, ph = expf(d3) * h;
        float x1 = fminf(fmaxf(pcx - 0.5f * pw, 0.0f), IMGF);
        float y1 = fminf(fmaxf(pcy - 0.5f * ph, 0.0f), IMGF);
        float x2 = fminf(fmaxf(pcx + 0.5f * pw, 0.0f), IMGF);
        float y2 = fminf(fmaxf(pcy + 0.5f * ph, 0.0f), IMGF);
        ws->cand[cnt] = make_float4(x1, y1, x2, y2);
    }
}

// ---------------------------------------------------------------------------
// Kernel 4: build the pairwise suppression bitmask.
// ---------------------------------------------------------------------------
__global__ __launch_bounds__(256) void nms_mask_k(Ws* __restrict__ ws) {
    const int i = blockIdx.x;
    const int lane = threadIdx.x & 63;
    const int wave = threadIdx.x >> 6;
    const float4 bi = ws->cand[i];
    const float ai = (bi.z - bi.x) * (bi.w - bi.y);
    for (int wd = wave; wd < NWORD; wd += 4) {
        int j = wd * 64 + lane;
        bool bit = false;
        if (j < K_PRE && j > i) {
            float4 bj = ws->cand[j];
            float aj = (bj.z - bj.x) * (bj.w - bj.y);
            float xx1 = fmaxf(bi.x, bj.x);
            float yy1 = fmaxf(bi.y, bj.y);
            float xx2 = fminf(bi.z, bj.z);
            float yy2 = fminf(bi.w, bj.w);
            float ww = fmaxf(xx2 - xx1, 0.0f);
            float hh = fmaxf(yy2 - yy1, 0.0f);
            float inter = ww * hh;
            float iou = inter / (ai + aj - inter + 1e-6f);
            bit = iou > IOU_THR;
        }
        u64 bal = __ballot(bit);
        if (lane == 0) ws->mask[(size_t)i * NWORD + wd] = bal;
    }
}

// ---------------------------------------------------------------------------
// Kernel 5: greedy scan, owner-lane formulation + early exit once K_POST
// rows are kept (downstream only consumes the first K_POST kept rows).
// ---------------------------------------------------------------------------
__global__ __launch_bounds__(512) void nms_scan_k(Ws* __restrict__ ws) {
    __shared__ __align__(16) u64 sbuf[2][TROWS * NWORD];
    __shared__ int s_stop;
    const int tid = threadIdx.x;
    const int lane = tid & 63;
    const int wave = tid >> 6;
    const int lmod = lane & 31;
    const u64* __restrict__ mask = ws->mask;

    {
        const ulonglong2* src = (const ulonglong2*)mask;
        ulonglong2* dst = (ulonglong2*)sbuf[0];
        for (int e = tid; e < TROWS * NWORD / 2; e += 512) dst[e] = src[e];
    }
    if (tid == 0) s_stop = 0;
    __syncthreads();

    u64 supp = 0ull;
    int kcnt = 0;
    int decided = 0;
    for (int t = 0; t < NTILE; ++t) {
        const int base = t * TROWS;
        const int nb = min(TROWS, K_PRE - base);
        if (wave == 0) {
            const u64* sm = sbuf[t & 1];
            u64 A[CH], B[CH];
#pragma unroll
            for (int b = 0; b < CH; ++b) A[b] = sm[b * NWORD + lmod];
            for (int s = 0; s < nb; s += 2 * CH) {
                const bool hasB = (s + CH) < nb;
                if (hasB) {
#pragma unroll
                    for (int b = 0; b < CH; ++b) B[b] = sm[(s + CH + b) * NWORD + lmod];
                }
                {
                    const int w = (base + s) >> 6;
                    const int bofs = (base + s) & 63;
                    u64 keptw = 0ull;
                    if (lane == w) {
                        u64 cur = supp;
#pragma unroll
                        for (int b = 0; b < CH; ++b) {
                            u64 bit = (cur >> (bofs + b)) & 1ull;
                            u64 sel = bit - 1ull;
                            cur |= A[b] & sel;
                            keptw |= sel & (1ull << b);
                        }
                        supp = cur;
                    }
                    u64 kb = __shfl(keptw, w);
                    kcnt += __popcll(kb);
#pragma unroll
                    for (int b = 0; b < CH; ++b) {
                        u64 sel = 0ull - ((kb >> b) & 1ull);
                        supp |= A[b] & sel;
                    }
                }
                if (hasB) {
                    if (s + 2 * CH < nb) {
#pragma unroll
                        for (int b = 0; b < CH; ++b)
                            A[b] = sm[(s + 2 * CH + b) * NWORD + lmod];
                    }
                    const int w = (base + s + CH) >> 6;
                    const int bofs = (base + s + CH) & 63;
                    u64 keptw = 0ull;
                    if (lane == w) {
                        u64 cur = supp;
#pragma unroll
                        for (int b = 0; b < CH; ++b) {
                            u64 bit = (cur >> (bofs + b)) & 1ull;
                            u64 sel = bit - 1ull;
                            cur |= B[b] & sel;
                            keptw |= sel & (1ull << b);
                        }
                        supp = cur;
                    }
                    u64 kb = __shfl(keptw, w);
                    kcnt += __popcll(kb);
#pragma unroll
                    for (int b = 0; b < CH; ++b) {
                        u64 sel = 0ull - ((kb >> b) & 1ull);
                        supp |= B[b] & sel;
                    }
                }
            }
            decided = base + nb;
            if (lane == 0 && kcnt >= K_POST) s_stop = 1;
        } else if (t + 1 < NTILE) {
            const int nbase = (t + 1) * TROWS;
            const int npairs = (min(TROWS, K_PRE - nbase) * NWORD) / 2;
            const ulonglong2* src = (const ulonglong2*)(mask + (size_t)nbase * NWORD);
            ulonglong2* dst = (ulonglong2*)sbuf[(t + 1) & 1];
            for (int e = tid - 64; e < npairs; e += 448) dst[e] = src[e];
        }
        __syncthreads();
        if (s_stop) break;
    }

    if (wave == 0) {
        u64 valid;
        if (lane < NWORD - 1)       valid = ~0ull;
        else if (lane == NWORD - 1) valid = (1ull << (K_PRE - (NWORD - 1) * 64)) - 1ull;
        else                        valid = 0ull;
        const int dw = decided - lane * 64;
        const u64 dmask = (dw <= 0) ? 0ull : ((dw >= 64) ? ~0ull : ((1ull << dw) - 1ull));
        u64 keepw = (~supp) & valid & dmask;
        int cnt = __popcll(keepw);
        int incl = cnt;
        for (int off = 1; off < 64; off <<= 1) {
            int t = __shfl_up(incl, off);
            if (lane >= off) incl += t;
        }
        int pos = incl - cnt;
        u64 kw = keepw;
        while (kw) {
            int b = __ffsll((unsigned long long)kw) - 1;
            kw &= kw - 1ull;
            if (pos < K_POST) ws->rows[pos] = lane * 64 + b;
            ++pos;
        }
        int total = __shfl(incl, 63);
        if (lane == 0) ws->nk = total;
        int start = total < K_POST ? total : K_POST;
        for (int r = start + lane; r < K_POST; r += 64) ws->rows[r] = -1;
    }
}

// ---------------------------------------------------------------------------
// Kernel 6: ROIAlign, XCD-pinned channel groups + float2 corner loads
// (REVERTED to round-9 version — measured 57us. Round-10's row-span LDS
// staging regressed 5.6x: SPAN=201 bank conflicts (4.4M cycles) + 131k tiny
// blocks of per-block overhead. Scattered-but-register-resident gathers win
// when per-block work is this small.)
// ---------------------------------------------------------------------------
__global__ __launch_bounds__(256) void roi_k(const float* __restrict__ feat,
                                             const Ws* __restrict__ ws,
                                             float* __restrict__ out) {
    const int g = blockIdx.x;
    const int q = g & 7;
    const int r = g >> 3;
    const int cbase = q * CG;
    float* oblk = out + (size_t)r * (FC * 49) + (size_t)cbase * 49;
    const int row = ws->rows[r];
    const int tid = threadIdx.x;

    if (row < 0) {
        for (int e = tid; e < CG * 49; e += 256) oblk[e] = 0.0f;
        return;
    }
    if (tid >= 245) return;                 // 5 channel slots x 49 bins

    const int p = tid % 49;
    const int cslot = tid / 49;             // 0..4
    const int oy = p / 7, ox = p % 7;

    const float4 bx = ws->cand[row];
    const float x1 = bx.x * SCALE, y1 = bx.y * SCALE;
    const float x2 = bx.z * SCALE, y2 = bx.w * SCALE;
    const float rw = fmaxf(x2 - x1, 1.0f);
    const float rh = fmaxf(y2 - y1, 1.0f);
    const float stepx = rw / 14.0f;
    const float stepy = rh / 14.0f;

    int    off0[4], off1[4];                // row-iy0 / row-iy1 base offsets
    float4 w4[4];                           // (w00,w01,w10,w11) * 0.25
#pragma unroll
    for (int sub = 0; sub < 4; ++sub) {
        const int sy = sub >> 1, sx = sub & 1;
        float yy = y1 + ((float)(2 * oy + sy) + 0.5f) * stepy;
        float y = fminf(fmaxf(yy, 0.0f), (float)(FH - 1));
        float fy0 = floorf(y);
        int iy0 = (int)fy0;
        int iy1 = min(iy0 + 1, FH - 1);
        float ly = y - fy0;
        float xx = x1 + ((float)(2 * ox + sx) + 0.5f) * stepx;
        float x = fminf(fmaxf(xx, 0.0f), (float)(FW - 1));
        float fx0 = floorf(x);
        int ix0 = (int)fx0;
        float lx = x - fx0;
        float wxl, wxr; int base;
        if (ix0 >= FW - 1) { base = FW - 2; wxl = 0.0f; wxr = 1.0f; } // lx==0 here
        else               { base = ix0;    wxl = 1.0f - lx; wxr = lx; }
        float wy0 = 1.0f - ly, wy1 = ly;
        off0[sub] = iy0 * FW + base;
        off1[sub] = iy1 * FW + base;
        w4[sub] = make_float4(wy0 * wxl * 0.25f, wy0 * wxr * 0.25f,
                              wy1 * wxl * 0.25f, wy1 * wxr * 0.25f);
    }

#pragma unroll
    for (int m = 0; m < 4; ++m) {
        const int c0 = cslot + 10 * m;
        const int c1 = c0 + 5;
        const bool v0 = c0 < CG;
        const bool v1 = c1 < CG;
        const float* f0 = feat + (size_t)(cbase + (v0 ? c0 : 0)) * (FH * FW);
        const float* f1 = feat + (size_t)(cbase + (v1 ? c1 : 0)) * (FH * FW);
        f2u r0[8], r1[8];
#pragma unroll
        for (int sub = 0; sub < 4; ++sub) {
            r0[2 * sub]     = *(const f2u*)(f0 + off0[sub]);
            r0[2 * sub + 1] = *(const f2u*)(f0 + off1[sub]);
            r1[2 * sub]     = *(const f2u*)(f1 + off0[sub]);
            r1[2 * sub + 1] = *(const f2u*)(f1 + off1[sub]);
        }
        float a0 = 0.0f, a1 = 0.0f;
#pragma unroll
        for (int sub = 0; sub < 4; ++sub) {
            a0 += w4[sub].x * r0[2 * sub].x + w4[sub].y * r0[2 * sub].y
                + w4[sub].z * r0[2 * sub + 1].x + w4[sub].w * r0[2 * sub + 1].y;
            a1 += w4[sub].x * r1[2 * sub].x + w4[sub].y * r1[2 * sub].y
                + w4[sub].z * r1[2 * sub + 1].x + w4[sub].w * r1[2 * sub + 1].y;
        }
        if (v0) oblk[c0 * 49 + p] = a0;
        if (v1) oblk[c1 * 49 + p] = a1;
    }
}

extern "C" void kernel_launch(void* const* d_in, const int* in_sizes, int n_in,
                              void* d_out, int out_size, void* d_ws, size_t ws_size,
                              hipStream_t stream) {
    const float* feature    = (const float*)d_in[0];
    const float* objectness = (const float*)d_in[1];
    const float* deltas     = (const float*)d_in[2];
    const float* anchors    = (const float*)d_in[3];
    Ws* ws = (Ws*)d_ws;
    uint32_t* hist = (uint32_t*)ws->mask;   // alias: hist lives in (pre-)mask space
    float* out = (float*)d_out;

    hipLaunchKernelGGL(zero_k, dim3(1), dim3(1024), 0, stream, ws);
    hipLaunchKernelGGL(hist_k, dim3(256), dim3(256), 0, stream, objectness, hist);
    hipLaunchKernelGGL(gather_k, dim3((N_ANCH / 4 + 255) / 256), dim3(256), 0, stream,
                       objectness, hist, ws);
    hipLaunchKernelGGL(rank_decode_k, dim3(CAP / (256 / TPE)), dim3(256), 0, stream,
                       deltas, anchors, ws);
    hipLaunchKernelGGL(nms_mask_k, dim3(K_PRE), dim3(256), 0, stream, ws);
    hipLaunchKernelGGL(nms_scan_k, dim3(1), dim3(512), 0, stream, ws);
    hipLaunchKernelGGL(roi_k, dim3(8 * K_POST), dim3(256), 0, stream, feature, ws, out);
}